// Round 1
// baseline (878.999 us; speedup 1.0000x reference)
//
#include <hip/hip_runtime.h>

#define N_NODES 50000
#define N_EDGES 800000
#define E_TOT   850000
#define F_IN    128
#define HC      256      // H * C_hid
#define NH      8
#define C_OUT   10
#define N_GRAPH 128
#define NBLK    49       // ceil(N_NODES / 1024)

__device__ __forceinline__ float lrelu(float x){ return x > 0.f ? x : 0.2f * x; }
__device__ __forceinline__ float elu1(float x){ return x > 0.f ? x : (__expf(x) - 1.f); }

// ---- zero the accumulators we rely on (ws is poisoned 0xAA each call) ----
__global__ void k_init(int* __restrict__ deg, float* __restrict__ gsum, float* __restrict__ gcnt){
    int i = blockIdx.x * 256 + threadIdx.x;
    if (i < N_NODES) deg[i] = 0;
    if (i < N_GRAPH * C_OUT) gsum[i] = 0.f;
    if (i < N_GRAPH) gcnt[i] = 0.f;
}

// ---- GEMM1: xh1[N,256] = x[N,128] @ W1[128,256], fp32, 4x4 microtile ----
__global__ __launch_bounds__(256) void k_gemm1(const float* __restrict__ x,
                                               const float* __restrict__ W,
                                               float* __restrict__ xh){
    const int tx = threadIdx.x & 15;    // col group (4 cols)
    const int ty = threadIdx.x >> 4;    // row group (4 rows)
    const int bx = blockIdx.x & 3;      // 256/64 col blocks
    const int by = blockIdx.x >> 2;
    const int c0 = bx * 64 + tx * 4;
    const int r0 = by * 64 + ty * 4;
    const float* xr0; const float* xr1; const float* xr2; const float* xr3;
    {
        int r = r0;     if (r >= N_NODES) r = N_NODES - 1; xr0 = x + (size_t)r * F_IN;
        r = r0 + 1;     if (r >= N_NODES) r = N_NODES - 1; xr1 = x + (size_t)r * F_IN;
        r = r0 + 2;     if (r >= N_NODES) r = N_NODES - 1; xr2 = x + (size_t)r * F_IN;
        r = r0 + 3;     if (r >= N_NODES) r = N_NODES - 1; xr3 = x + (size_t)r * F_IN;
    }
    const float* Wp = W + c0;
    float acc[4][4] = {};
    #pragma unroll 8
    for (int k = 0; k < F_IN; k++){
        float4 b = *(const float4*)(Wp + (size_t)k * HC);
        float a0 = xr0[k], a1 = xr1[k], a2 = xr2[k], a3 = xr3[k];
        acc[0][0] += a0*b.x; acc[0][1] += a0*b.y; acc[0][2] += a0*b.z; acc[0][3] += a0*b.w;
        acc[1][0] += a1*b.x; acc[1][1] += a1*b.y; acc[1][2] += a1*b.z; acc[1][3] += a1*b.w;
        acc[2][0] += a2*b.x; acc[2][1] += a2*b.y; acc[2][2] += a2*b.z; acc[2][3] += a2*b.w;
        acc[3][0] += a3*b.x; acc[3][1] += a3*b.y; acc[3][2] += a3*b.z; acc[3][3] += a3*b.w;
    }
    #pragma unroll
    for (int i = 0; i < 4; i++){
        int r = r0 + i;
        if (r < N_NODES){
            float4 o = make_float4(acc[i][0], acc[i][1], acc[i][2], acc[i][3]);
            *(float4*)(xh + (size_t)r * HC + c0) = o;
        }
    }
}

// ---- attention scalars layer1: a_src/a_dst [N,8] ----
__global__ void k_ascore1(const float* __restrict__ xh,
                          const float* __restrict__ atts, const float* __restrict__ attd,
                          float* __restrict__ a_s, float* __restrict__ a_d){
    int t = blockIdx.x * 256 + threadIdx.x;
    if (t >= N_NODES * NH) return;
    int h = t & 7;
    const float4* row = (const float4*)(xh + (size_t)(t >> 3) * HC + h * 32);
    const float4* s4  = (const float4*)(atts + h * 32);
    const float4* d4  = (const float4*)(attd + h * 32);
    float s = 0.f, d = 0.f;
    #pragma unroll
    for (int c = 0; c < 8; c++){
        float4 v = row[c], a = s4[c], b = d4[c];
        s += v.x*a.x + v.y*a.y + v.z*a.z + v.w*a.w;
        d += v.x*b.x + v.y*b.y + v.z*b.z + v.w*b.w;
    }
    a_s[t] = s; a_d[t] = d;
}

// ---- CSR build: degree histogram ----
__global__ void k_deg(const int* __restrict__ ei, int* __restrict__ deg){
    int e = blockIdx.x * 256 + threadIdx.x;
    if (e >= E_TOT) return;
    int dst = (e < N_EDGES) ? ei[N_EDGES + e] : (e - N_EDGES);
    atomicAdd(deg + dst, 1);
}

// ---- per-1024-chunk sums ----
__global__ void k_bsum(const int* __restrict__ deg, int* __restrict__ bsum){
    int b = blockIdx.x;
    int v = 0;
    for (int i = threadIdx.x; i < 1024; i += 256){
        int idx = b * 1024 + i;
        if (idx < N_NODES) v += deg[idx];
    }
    #pragma unroll
    for (int off = 1; off < 64; off <<= 1) v += __shfl_xor(v, off, 64);
    __shared__ int sd[4];
    if ((threadIdx.x & 63) == 0) sd[threadIdx.x >> 6] = v;
    __syncthreads();
    if (threadIdx.x == 0) bsum[b] = sd[0] + sd[1] + sd[2] + sd[3];
}

// ---- scan of chunk sums (single wave) ----
__global__ void k_scanb(const int* __restrict__ bsum, int* __restrict__ bexcl, int* __restrict__ rowp){
    int l = threadIdx.x;            // 64 threads
    int v = (l < NBLK) ? bsum[l] : 0;
    int incl = v;
    #pragma unroll
    for (int off = 1; off < 64; off <<= 1){
        int t = __shfl_up(incl, off, 64);
        if (l >= off) incl += t;
    }
    if (l < NBLK) bexcl[l] = incl - v;
    if (l == 0) rowp[N_NODES] = E_TOT;
}

// ---- per-chunk Hillis-Steele scan -> row_ptr, cursor ----
__global__ __launch_bounds__(1024) void k_scan(const int* __restrict__ deg, const int* __restrict__ bexcl,
                                               int* __restrict__ rowp, int* __restrict__ cur){
    __shared__ int sd[1024];
    int b = blockIdx.x;
    int i = b * 1024 + threadIdx.x;
    int v = (i < N_NODES) ? deg[i] : 0;
    sd[threadIdx.x] = v;
    __syncthreads();
    for (int off = 1; off < 1024; off <<= 1){
        int t = (threadIdx.x >= off) ? sd[threadIdx.x - off] : 0;
        __syncthreads();
        sd[threadIdx.x] += t;
        __syncthreads();
    }
    if (i < N_NODES){
        int excl = sd[threadIdx.x] - v + bexcl[b];
        rowp[i] = excl;
        cur[i]  = excl;
    }
}

// ---- scatter edges into CSR (src values), order within segment arbitrary ----
__global__ void k_scatter(const int* __restrict__ ei, int* __restrict__ cur, int* __restrict__ col){
    int e = blockIdx.x * 256 + threadIdx.x;
    if (e >= E_TOT) return;
    int s, d;
    if (e < N_EDGES){ s = ei[e]; d = ei[N_EDGES + e]; }
    else { s = e - N_EDGES; d = s; }
    int slot = atomicAdd(cur + d, 1);
    col[slot] = s;
}

// ---- layer-1 aggregation: one wave per dst node, lane owns float4 of 256-wide row ----
__global__ __launch_bounds__(256) void k_agg1(const float* __restrict__ xh,
                                              const float* __restrict__ a_s, const float* __restrict__ a_d,
                                              const int* __restrict__ rowp, const int* __restrict__ col,
                                              const float* __restrict__ bias, float* __restrict__ h1){
    int wave = threadIdx.x >> 6, lane = threadIdx.x & 63;
    int n = blockIdx.x * 4 + wave;
    if (n >= N_NODES) return;
    int h = lane >> 3;
    float adh = a_d[n * NH + h];
    int s0 = rowp[n], s1 = rowp[n + 1];
    const float4* xv = (const float4*)xh;
    float4 acc = make_float4(0.f, 0.f, 0.f, 0.f);
    float den = 0.f;
    for (int idx = s0; idx < s1; idx++){
        int s = col[idx];
        float w = __expf(lrelu(a_s[s * NH + h] + adh));
        den += w;
        float4 v = xv[(size_t)s * 64 + lane];
        acc.x += w * v.x; acc.y += w * v.y; acc.z += w * v.z; acc.w += w * v.w;
    }
    float rden = 1.f / den;
    float4 bb = ((const float4*)bias)[lane];
    float4 r;
    r.x = elu1(acc.x * rden + bb.x);
    r.y = elu1(acc.y * rden + bb.y);
    r.z = elu1(acc.z * rden + bb.z);
    r.w = elu1(acc.w * rden + bb.w);
    ((float4*)h1)[(size_t)n * 64 + lane] = r;
}

// ---- transpose W2 [256,10] -> W2t [10,256] ----
__global__ void k_w2t(const float* __restrict__ W2, float* __restrict__ W2t){
    for (int i = threadIdx.x; i < HC * C_OUT; i += 256){
        int k = i / C_OUT, c = i % C_OUT;
        W2t[c * HC + k] = W2[i];
    }
}

// ---- layer-2 projection + attention scalars: wave per node ----
__global__ __launch_bounds__(256) void k_gemm2(const float* __restrict__ h1, const float* __restrict__ W2t,
                                               const float* __restrict__ atts, const float* __restrict__ attd,
                                               float* __restrict__ xh2, float* __restrict__ a_s, float* __restrict__ a_d){
    int wave = threadIdx.x >> 6, lane = threadIdx.x & 63;
    int n = blockIdx.x * 4 + wave;
    if (n >= N_NODES) return;
    float4 hv = ((const float4*)h1)[(size_t)n * 64 + lane];
    float acc[C_OUT];
    #pragma unroll
    for (int c = 0; c < C_OUT; c++){
        float4 w = ((const float4*)(W2t + c * HC))[lane];
        acc[c] = hv.x*w.x + hv.y*w.y + hv.z*w.z + hv.w*w.w;
    }
    #pragma unroll
    for (int c = 0; c < C_OUT; c++){
        #pragma unroll
        for (int off = 32; off > 0; off >>= 1) acc[c] += __shfl_xor(acc[c], off, 64);
    }
    if (lane == 0){
        float s = 0.f, d = 0.f;
        #pragma unroll
        for (int c = 0; c < C_OUT; c++){
            xh2[n * C_OUT + c] = acc[c];
            s += acc[c] * atts[c];
            d += acc[c] * attd[c];
        }
        a_s[n] = s; a_d[n] = d;
    }
}

// ---- layer-2 aggregation + elu + fused mean-pool accumulation ----
__global__ __launch_bounds__(256) void k_agg2(const float* __restrict__ xh2,
                                              const float* __restrict__ a_s, const float* __restrict__ a_d,
                                              const int* __restrict__ rowp, const int* __restrict__ col,
                                              const float* __restrict__ b2, const int* __restrict__ batch,
                                              float* __restrict__ gsum, float* __restrict__ gcnt){
    int wave = threadIdx.x >> 6, lane = threadIdx.x & 63;
    int n = blockIdx.x * 4 + wave;
    if (n >= N_NODES) return;
    float adn = a_d[n];
    int s0 = rowp[n], s1 = rowp[n + 1];
    float acc[C_OUT] = {};
    float den = 0.f;
    for (int idx = s0 + lane; idx < s1; idx += 64){
        int s = col[idx];
        float w = __expf(lrelu(a_s[s] + adn));
        den += w;
        const float* xr = xh2 + s * C_OUT;
        #pragma unroll
        for (int c = 0; c < C_OUT; c++) acc[c] += w * xr[c];
    }
    #pragma unroll
    for (int off = 32; off > 0; off >>= 1) den += __shfl_xor(den, off, 64);
    #pragma unroll
    for (int c = 0; c < C_OUT; c++){
        #pragma unroll
        for (int off = 32; off > 0; off >>= 1) acc[c] += __shfl_xor(acc[c], off, 64);
    }
    if (lane == 0){
        int g = batch[n];
        float rden = 1.f / den;
        #pragma unroll
        for (int c = 0; c < C_OUT; c++){
            float v = elu1(acc[c] * rden + b2[c]);
            atomicAdd(gsum + g * C_OUT + c, v);
        }
        atomicAdd(gcnt + g, 1.f);
    }
}

// ---- final: per-graph mean + log_softmax ----
__global__ void k_final(const float* __restrict__ gsum, const float* __restrict__ gcnt, float* __restrict__ out){
    int g = threadIdx.x;
    if (g >= N_GRAPH) return;
    float cnt = gcnt[g];
    if (cnt < 1.f) cnt = 1.f;
    float v[C_OUT];
    float m = -1e30f;
    #pragma unroll
    for (int c = 0; c < C_OUT; c++){
        v[c] = gsum[g * C_OUT + c] / cnt;
        m = fmaxf(m, v[c]);
    }
    float sum = 0.f;
    #pragma unroll
    for (int c = 0; c < C_OUT; c++) sum += __expf(v[c] - m);
    float lse = m + __logf(sum);
    #pragma unroll
    for (int c = 0; c < C_OUT; c++) out[g * C_OUT + c] = v[c] - lse;
}

extern "C" void kernel_launch(void* const* d_in, const int* in_sizes, int n_in,
                              void* d_out, int out_size, void* d_ws, size_t ws_size,
                              hipStream_t stream){
    const float* x    = (const float*)d_in[0];
    const int*   ei   = (const int*)d_in[1];
    const int*   batch= (const int*)d_in[2];
    const float* W1   = (const float*)d_in[3];
    const float* as1  = (const float*)d_in[4];
    const float* ad1  = (const float*)d_in[5];
    const float* b1   = (const float*)d_in[6];
    const float* W2   = (const float*)d_in[7];
    const float* as2v = (const float*)d_in[8];
    const float* ad2v = (const float*)d_in[9];
    const float* b2   = (const float*)d_in[10];
    float* out = (float*)d_out;

    // workspace carve-up (~111 MB total), 256B aligned
    char* ws = (char*)d_ws;
    size_t off = 0;
    auto alloc = [&](size_t bytes)->char*{
        char* p = ws + off;
        off = (off + bytes + 255) & ~(size_t)255;
        return p;
    };
    float* xh1  = (float*)alloc((size_t)N_NODES * HC * 4);
    float* h1   = (float*)alloc((size_t)N_NODES * HC * 4);
    float* asc1 = (float*)alloc((size_t)N_NODES * NH * 4);
    float* adc1 = (float*)alloc((size_t)N_NODES * NH * 4);
    int*   deg  = (int*)alloc((size_t)N_NODES * 4);
    int*   rowp = (int*)alloc((size_t)(N_NODES + 1) * 4);
    int*   cur  = (int*)alloc((size_t)N_NODES * 4);
    int*   col  = (int*)alloc((size_t)E_TOT * 4);
    int*   bsum = (int*)alloc(64 * 4);
    int*   bexcl= (int*)alloc(64 * 4);
    float* xh2  = (float*)alloc((size_t)N_NODES * C_OUT * 4);
    float* asc2 = (float*)alloc((size_t)N_NODES * 4);
    float* adc2 = (float*)alloc((size_t)N_NODES * 4);
    float* W2t  = (float*)alloc((size_t)HC * C_OUT * 4);
    float* gsum = (float*)alloc((size_t)N_GRAPH * C_OUT * 4);
    float* gcnt = (float*)alloc((size_t)N_GRAPH * 4);
    (void)ws_size; (void)in_sizes; (void)n_in; (void)out_size;

    hipLaunchKernelGGL(k_init,    dim3(196),  dim3(256), 0, stream, deg, gsum, gcnt);
    hipLaunchKernelGGL(k_gemm1,   dim3(3128), dim3(256), 0, stream, x, W1, xh1);
    hipLaunchKernelGGL(k_ascore1, dim3((N_NODES*NH + 255)/256), dim3(256), 0, stream, xh1, as1, ad1, asc1, adc1);
    hipLaunchKernelGGL(k_deg,     dim3((E_TOT + 255)/256), dim3(256), 0, stream, ei, deg);
    hipLaunchKernelGGL(k_bsum,    dim3(NBLK), dim3(256), 0, stream, deg, bsum);
    hipLaunchKernelGGL(k_scanb,   dim3(1),    dim3(64),  0, stream, bsum, bexcl, rowp);
    hipLaunchKernelGGL(k_scan,    dim3(NBLK), dim3(1024),0, stream, deg, bexcl, rowp, cur);
    hipLaunchKernelGGL(k_scatter, dim3((E_TOT + 255)/256), dim3(256), 0, stream, ei, cur, col);
    hipLaunchKernelGGL(k_agg1,    dim3((N_NODES + 3)/4), dim3(256), 0, stream, xh1, asc1, adc1, rowp, col, b1, h1);
    hipLaunchKernelGGL(k_w2t,     dim3(1),    dim3(256), 0, stream, W2, W2t);
    hipLaunchKernelGGL(k_gemm2,   dim3((N_NODES + 3)/4), dim3(256), 0, stream, h1, W2t, as2v, ad2v, xh2, asc2, adc2);
    hipLaunchKernelGGL(k_agg2,    dim3((N_NODES + 3)/4), dim3(256), 0, stream, xh2, asc2, adc2, rowp, col, b2, batch, gsum, gcnt);
    hipLaunchKernelGGL(k_final,   dim3(1),    dim3(128), 0, stream, gsum, gcnt, out);
}

// Round 2
// 518.623 us; speedup vs baseline: 1.6949x; 1.6949x over previous
//
#include <hip/hip_runtime.h>

#define N_NODES 50000
#define N_EDGES 800000
#define E_TOT   850000
#define F_IN    128
#define HC      256      // H * C_hid
#define NH      8
#define C_OUT   10
#define N_GRAPH 128
#define NBLK    49       // ceil(N_NODES / 1024)

__device__ __forceinline__ float lrelu(float x){ return x > 0.f ? x : 0.2f * x; }
__device__ __forceinline__ float elu1(float x){ return x > 0.f ? x : (__expf(x) - 1.f); }

// ---- zero the accumulators we rely on (ws is poisoned 0xAA each call) ----
__global__ void k_init(int* __restrict__ deg){
    int i = blockIdx.x * 256 + threadIdx.x;
    if (i < N_NODES) deg[i] = 0;
}

// ---- GEMM1: xh1[N,256] = x[N,128] @ W1[128,256], fp32, 4x4 microtile ----
__global__ __launch_bounds__(256) void k_gemm1(const float* __restrict__ x,
                                               const float* __restrict__ W,
                                               float* __restrict__ xh){
    const int tx = threadIdx.x & 15;    // col group (4 cols)
    const int ty = threadIdx.x >> 4;    // row group (4 rows)
    const int bx = blockIdx.x & 3;      // 256/64 col blocks
    const int by = blockIdx.x >> 2;
    const int c0 = bx * 64 + tx * 4;
    const int r0 = by * 64 + ty * 4;
    const float* xr0; const float* xr1; const float* xr2; const float* xr3;
    {
        int r = r0;     if (r >= N_NODES) r = N_NODES - 1; xr0 = x + (size_t)r * F_IN;
        r = r0 + 1;     if (r >= N_NODES) r = N_NODES - 1; xr1 = x + (size_t)r * F_IN;
        r = r0 + 2;     if (r >= N_NODES) r = N_NODES - 1; xr2 = x + (size_t)r * F_IN;
        r = r0 + 3;     if (r >= N_NODES) r = N_NODES - 1; xr3 = x + (size_t)r * F_IN;
    }
    const float* Wp = W + c0;
    float acc[4][4] = {};
    #pragma unroll 8
    for (int k = 0; k < F_IN; k++){
        float4 b = *(const float4*)(Wp + (size_t)k * HC);
        float a0 = xr0[k], a1 = xr1[k], a2 = xr2[k], a3 = xr3[k];
        acc[0][0] += a0*b.x; acc[0][1] += a0*b.y; acc[0][2] += a0*b.z; acc[0][3] += a0*b.w;
        acc[1][0] += a1*b.x; acc[1][1] += a1*b.y; acc[1][2] += a1*b.z; acc[1][3] += a1*b.w;
        acc[2][0] += a2*b.x; acc[2][1] += a2*b.y; acc[2][2] += a2*b.z; acc[2][3] += a2*b.w;
        acc[3][0] += a3*b.x; acc[3][1] += a3*b.y; acc[3][2] += a3*b.z; acc[3][3] += a3*b.w;
    }
    #pragma unroll
    for (int i = 0; i < 4; i++){
        int r = r0 + i;
        if (r < N_NODES){
            float4 o = make_float4(acc[i][0], acc[i][1], acc[i][2], acc[i][3]);
            *(float4*)(xh + (size_t)r * HC + c0) = o;
        }
    }
}

// ---- attention scalars layer1: a_src/a_dst [N,8] ----
__global__ void k_ascore1(const float* __restrict__ xh,
                          const float* __restrict__ atts, const float* __restrict__ attd,
                          float* __restrict__ a_s, float* __restrict__ a_d){
    int t = blockIdx.x * 256 + threadIdx.x;
    if (t >= N_NODES * NH) return;
    int h = t & 7;
    const float4* row = (const float4*)(xh + (size_t)(t >> 3) * HC + h * 32);
    const float4* s4  = (const float4*)(atts + h * 32);
    const float4* d4  = (const float4*)(attd + h * 32);
    float s = 0.f, d = 0.f;
    #pragma unroll
    for (int c = 0; c < 8; c++){
        float4 v = row[c], a = s4[c], b = d4[c];
        s += v.x*a.x + v.y*a.y + v.z*a.z + v.w*a.w;
        d += v.x*b.x + v.y*b.y + v.z*b.z + v.w*b.w;
    }
    a_s[t] = s; a_d[t] = d;
}

// ---- CSR build: degree histogram ----
__global__ void k_deg(const int* __restrict__ ei, int* __restrict__ deg){
    int e = blockIdx.x * 256 + threadIdx.x;
    if (e >= E_TOT) return;
    int dst = (e < N_EDGES) ? ei[N_EDGES + e] : (e - N_EDGES);
    atomicAdd(deg + dst, 1);
}

// ---- per-1024-chunk sums ----
__global__ void k_bsum(const int* __restrict__ deg, int* __restrict__ bsum){
    int b = blockIdx.x;
    int v = 0;
    for (int i = threadIdx.x; i < 1024; i += 256){
        int idx = b * 1024 + i;
        if (idx < N_NODES) v += deg[idx];
    }
    #pragma unroll
    for (int off = 1; off < 64; off <<= 1) v += __shfl_xor(v, off, 64);
    __shared__ int sd[4];
    if ((threadIdx.x & 63) == 0) sd[threadIdx.x >> 6] = v;
    __syncthreads();
    if (threadIdx.x == 0) bsum[b] = sd[0] + sd[1] + sd[2] + sd[3];
}

// ---- scan of chunk sums (single wave) ----
__global__ void k_scanb(const int* __restrict__ bsum, int* __restrict__ bexcl, int* __restrict__ rowp){
    int l = threadIdx.x;            // 64 threads
    int v = (l < NBLK) ? bsum[l] : 0;
    int incl = v;
    #pragma unroll
    for (int off = 1; off < 64; off <<= 1){
        int t = __shfl_up(incl, off, 64);
        if (l >= off) incl += t;
    }
    if (l < NBLK) bexcl[l] = incl - v;
    if (l == 0) rowp[N_NODES] = E_TOT;
}

// ---- per-chunk Hillis-Steele scan -> row_ptr, cursor ----
__global__ __launch_bounds__(1024) void k_scan(const int* __restrict__ deg, const int* __restrict__ bexcl,
                                               int* __restrict__ rowp, int* __restrict__ cur){
    __shared__ int sd[1024];
    int b = blockIdx.x;
    int i = b * 1024 + threadIdx.x;
    int v = (i < N_NODES) ? deg[i] : 0;
    sd[threadIdx.x] = v;
    __syncthreads();
    for (int off = 1; off < 1024; off <<= 1){
        int t = (threadIdx.x >= off) ? sd[threadIdx.x - off] : 0;
        __syncthreads();
        sd[threadIdx.x] += t;
        __syncthreads();
    }
    if (i < N_NODES){
        int excl = sd[threadIdx.x] - v + bexcl[b];
        rowp[i] = excl;
        cur[i]  = excl;
    }
}

// ---- scatter edges into CSR (src values), order within segment arbitrary ----
__global__ void k_scatter(const int* __restrict__ ei, int* __restrict__ cur, int* __restrict__ col){
    int e = blockIdx.x * 256 + threadIdx.x;
    if (e >= E_TOT) return;
    int s, d;
    if (e < N_EDGES){ s = ei[e]; d = ei[N_EDGES + e]; }
    else { s = e - N_EDGES; d = s; }
    int slot = atomicAdd(cur + d, 1);
    col[slot] = s;
}

// ---- layer-1 aggregation: one wave per dst node, lane owns float4 of 256-wide row ----
__global__ __launch_bounds__(256) void k_agg1(const float* __restrict__ xh,
                                              const float* __restrict__ a_s, const float* __restrict__ a_d,
                                              const int* __restrict__ rowp, const int* __restrict__ col,
                                              const float* __restrict__ bias, float* __restrict__ h1){
    int wave = threadIdx.x >> 6, lane = threadIdx.x & 63;
    int n = blockIdx.x * 4 + wave;
    if (n >= N_NODES) return;
    int h = lane >> 3;
    float adh = a_d[n * NH + h];
    int s0 = rowp[n], s1 = rowp[n + 1];
    const float4* xv = (const float4*)xh;
    float4 acc = make_float4(0.f, 0.f, 0.f, 0.f);
    float den = 0.f;
    for (int idx = s0; idx < s1; idx++){
        int s = col[idx];
        float w = __expf(lrelu(a_s[s * NH + h] + adh));
        den += w;
        float4 v = xv[(size_t)s * 64 + lane];
        acc.x += w * v.x; acc.y += w * v.y; acc.z += w * v.z; acc.w += w * v.w;
    }
    float rden = 1.f / den;
    float4 bb = ((const float4*)bias)[lane];
    float4 r;
    r.x = elu1(acc.x * rden + bb.x);
    r.y = elu1(acc.y * rden + bb.y);
    r.z = elu1(acc.z * rden + bb.z);
    r.w = elu1(acc.w * rden + bb.w);
    ((float4*)h1)[(size_t)n * 64 + lane] = r;
}

// ---- transpose W2 [256,10] -> W2t [10,256] ----
__global__ void k_w2t(const float* __restrict__ W2, float* __restrict__ W2t){
    for (int i = threadIdx.x; i < HC * C_OUT; i += 256){
        int k = i / C_OUT, c = i % C_OUT;
        W2t[c * HC + k] = W2[i];
    }
}

// ---- layer-2 projection + attention scalars: wave per node ----
__global__ __launch_bounds__(256) void k_gemm2(const float* __restrict__ h1, const float* __restrict__ W2t,
                                               const float* __restrict__ atts, const float* __restrict__ attd,
                                               float* __restrict__ xh2, float* __restrict__ a_s, float* __restrict__ a_d){
    int wave = threadIdx.x >> 6, lane = threadIdx.x & 63;
    int n = blockIdx.x * 4 + wave;
    if (n >= N_NODES) return;
    float4 hv = ((const float4*)h1)[(size_t)n * 64 + lane];
    float acc[C_OUT];
    #pragma unroll
    for (int c = 0; c < C_OUT; c++){
        float4 w = ((const float4*)(W2t + c * HC))[lane];
        acc[c] = hv.x*w.x + hv.y*w.y + hv.z*w.z + hv.w*w.w;
    }
    #pragma unroll
    for (int c = 0; c < C_OUT; c++){
        #pragma unroll
        for (int off = 32; off > 0; off >>= 1) acc[c] += __shfl_xor(acc[c], off, 64);
    }
    if (lane == 0){
        float s = 0.f, d = 0.f;
        #pragma unroll
        for (int c = 0; c < C_OUT; c++){
            xh2[n * C_OUT + c] = acc[c];
            s += acc[c] * atts[c];
            d += acc[c] * attd[c];
        }
        a_s[n] = s; a_d[n] = d;
    }
}

// ---- layer-2 aggregation + elu -> per-node h2[N,10] (no atomics) ----
__global__ __launch_bounds__(256) void k_agg2(const float* __restrict__ xh2,
                                              const float* __restrict__ a_s, const float* __restrict__ a_d,
                                              const int* __restrict__ rowp, const int* __restrict__ col,
                                              const float* __restrict__ b2,
                                              float* __restrict__ h2){
    int wave = threadIdx.x >> 6, lane = threadIdx.x & 63;
    int n = blockIdx.x * 4 + wave;
    if (n >= N_NODES) return;
    float adn = a_d[n];
    int s0 = rowp[n], s1 = rowp[n + 1];
    float acc[C_OUT] = {};
    float den = 0.f;
    for (int idx = s0 + lane; idx < s1; idx += 64){
        int s = col[idx];
        float w = __expf(lrelu(a_s[s] + adn));
        den += w;
        const float* xr = xh2 + s * C_OUT;
        #pragma unroll
        for (int c = 0; c < C_OUT; c++) acc[c] += w * xr[c];
    }
    #pragma unroll
    for (int off = 32; off > 0; off >>= 1) den += __shfl_xor(den, off, 64);
    #pragma unroll
    for (int c = 0; c < C_OUT; c++){
        #pragma unroll
        for (int off = 32; off > 0; off >>= 1) acc[c] += __shfl_xor(acc[c], off, 64);
    }
    if (lane == 0){
        float rden = 1.f / den;
        #pragma unroll
        for (int c = 0; c < C_OUT; c++)
            h2[(size_t)n * C_OUT + c] = elu1(acc[c] * rden + b2[c]);
    }
}

// ---- pooling + log_softmax: one block per graph (batch is sorted) ----
__global__ __launch_bounds__(256) void k_pool(const float* __restrict__ h2, const int* __restrict__ batch,
                                              float* __restrict__ out){
    int g = blockIdx.x;
    // binary search [lo, hi): nodes with batch[i] == g
    int l = 0, r = N_NODES;
    while (l < r){ int m = (l + r) >> 1; if (batch[m] < g) l = m + 1; else r = m; }
    int lo = l;
    l = 0; r = N_NODES;
    while (l < r){ int m = (l + r) >> 1; if (batch[m] < g + 1) l = m + 1; else r = m; }
    int hi = l;
    float acc[C_OUT] = {};
    for (int i = lo + (int)threadIdx.x; i < hi; i += 256){
        const float* row = h2 + (size_t)i * C_OUT;
        #pragma unroll
        for (int c = 0; c < C_OUT; c++) acc[c] += row[c];
    }
    // wave reduce
    #pragma unroll
    for (int c = 0; c < C_OUT; c++){
        #pragma unroll
        for (int off = 32; off > 0; off >>= 1) acc[c] += __shfl_xor(acc[c], off, 64);
    }
    __shared__ float sd[4][C_OUT];
    int wave = threadIdx.x >> 6, lane = threadIdx.x & 63;
    if (lane == 0){
        #pragma unroll
        for (int c = 0; c < C_OUT; c++) sd[wave][c] = acc[c];
    }
    __syncthreads();
    if (threadIdx.x == 0){
        float cnt = (float)(hi - lo);
        if (cnt < 1.f) cnt = 1.f;
        float v[C_OUT];
        float m = -1e30f;
        #pragma unroll
        for (int c = 0; c < C_OUT; c++){
            v[c] = (sd[0][c] + sd[1][c] + sd[2][c] + sd[3][c]) / cnt;
            m = fmaxf(m, v[c]);
        }
        float sum = 0.f;
        #pragma unroll
        for (int c = 0; c < C_OUT; c++) sum += __expf(v[c] - m);
        float lse = m + __logf(sum);
        #pragma unroll
        for (int c = 0; c < C_OUT; c++) out[g * C_OUT + c] = v[c] - lse;
    }
}

extern "C" void kernel_launch(void* const* d_in, const int* in_sizes, int n_in,
                              void* d_out, int out_size, void* d_ws, size_t ws_size,
                              hipStream_t stream){
    const float* x    = (const float*)d_in[0];
    const int*   ei   = (const int*)d_in[1];
    const int*   batch= (const int*)d_in[2];
    const float* W1   = (const float*)d_in[3];
    const float* as1  = (const float*)d_in[4];
    const float* ad1  = (const float*)d_in[5];
    const float* b1   = (const float*)d_in[6];
    const float* W2   = (const float*)d_in[7];
    const float* as2v = (const float*)d_in[8];
    const float* ad2v = (const float*)d_in[9];
    const float* b2   = (const float*)d_in[10];
    float* out = (float*)d_out;

    // workspace carve-up (~113 MB total), 256B aligned
    char* ws = (char*)d_ws;
    size_t off = 0;
    auto alloc = [&](size_t bytes)->char*{
        char* p = ws + off;
        off = (off + bytes + 255) & ~(size_t)255;
        return p;
    };
    float* xh1  = (float*)alloc((size_t)N_NODES * HC * 4);
    float* h1   = (float*)alloc((size_t)N_NODES * HC * 4);
    float* asc1 = (float*)alloc((size_t)N_NODES * NH * 4);
    float* adc1 = (float*)alloc((size_t)N_NODES * NH * 4);
    int*   deg  = (int*)alloc((size_t)N_NODES * 4);
    int*   rowp = (int*)alloc((size_t)(N_NODES + 1) * 4);
    int*   cur  = (int*)alloc((size_t)N_NODES * 4);
    int*   col  = (int*)alloc((size_t)E_TOT * 4);
    int*   bsum = (int*)alloc(64 * 4);
    int*   bexcl= (int*)alloc(64 * 4);
    float* xh2  = (float*)alloc((size_t)N_NODES * C_OUT * 4);
    float* asc2 = (float*)alloc((size_t)N_NODES * 4);
    float* adc2 = (float*)alloc((size_t)N_NODES * 4);
    float* W2t  = (float*)alloc((size_t)HC * C_OUT * 4);
    float* h2   = (float*)alloc((size_t)N_NODES * C_OUT * 4);
    (void)ws_size; (void)in_sizes; (void)n_in; (void)out_size;

    hipLaunchKernelGGL(k_init,    dim3(196),  dim3(256), 0, stream, deg);
    hipLaunchKernelGGL(k_gemm1,   dim3(3128), dim3(256), 0, stream, x, W1, xh1);
    hipLaunchKernelGGL(k_ascore1, dim3((N_NODES*NH + 255)/256), dim3(256), 0, stream, xh1, as1, ad1, asc1, adc1);
    hipLaunchKernelGGL(k_deg,     dim3((E_TOT + 255)/256), dim3(256), 0, stream, ei, deg);
    hipLaunchKernelGGL(k_bsum,    dim3(NBLK), dim3(256), 0, stream, deg, bsum);
    hipLaunchKernelGGL(k_scanb,   dim3(1),    dim3(64),  0, stream, bsum, bexcl, rowp);
    hipLaunchKernelGGL(k_scan,    dim3(NBLK), dim3(1024),0, stream, deg, bexcl, rowp, cur);
    hipLaunchKernelGGL(k_scatter, dim3((E_TOT + 255)/256), dim3(256), 0, stream, ei, cur, col);
    hipLaunchKernelGGL(k_agg1,    dim3((N_NODES + 3)/4), dim3(256), 0, stream, xh1, asc1, adc1, rowp, col, b1, h1);
    hipLaunchKernelGGL(k_w2t,     dim3(1),    dim3(256), 0, stream, W2, W2t);
    hipLaunchKernelGGL(k_gemm2,   dim3((N_NODES + 3)/4), dim3(256), 0, stream, h1, W2t, as2v, ad2v, xh2, asc2, adc2);
    hipLaunchKernelGGL(k_agg2,    dim3((N_NODES + 3)/4), dim3(256), 0, stream, xh2, asc2, adc2, rowp, col, b2, h2);
    hipLaunchKernelGGL(k_pool,    dim3(N_GRAPH), dim3(256), 0, stream, h2, batch, out);
}

// Round 4
// 468.439 us; speedup vs baseline: 1.8764x; 1.1071x over previous
//
#include <hip/hip_runtime.h>

#define N_NODES 50000
#define N_EDGES 800000
#define E_TOT   850000
#define F_IN    128
#define HC      256      // H * C_hid
#define NH      8
#define C_OUT   10
#define N_GRAPH 128
#define NBLK    49       // ceil(N_NODES / 1024)

__device__ __forceinline__ float lrelu(float x){ return x > 0.f ? x : 0.2f * x; }
__device__ __forceinline__ float elu1(float x){ return x > 0.f ? x : (__expf(x) - 1.f); }

// bf16 helpers (RNE), stored as packed uint
__device__ __forceinline__ unsigned short f2bf(float f){
    unsigned int u = __float_as_uint(f);
    return (unsigned short)((u + 0x7fffu + ((u >> 16) & 1u)) >> 16);
}
__device__ __forceinline__ unsigned int pack2(float a, float b){
    return (unsigned int)f2bf(a) | ((unsigned int)f2bf(b) << 16);
}
__device__ __forceinline__ void unp2(unsigned int p, float& a, float& b){
    a = __uint_as_float(p << 16);
    b = __uint_as_float(p & 0xffff0000u);
}

// ---- init: zero deg + attention-score accumulators; transpose W2 ----
__global__ void k_init(int* __restrict__ deg, float* __restrict__ a_s, float* __restrict__ a_d,
                       const float* __restrict__ W2, float* __restrict__ W2t){
    int i = blockIdx.x * 256 + threadIdx.x;
    if (i < N_NODES) deg[i] = 0;
    for (int j = i; j < N_NODES * NH; j += 196 * 256){
        a_s[j] = 0.f; a_d[j] = 0.f;
    }
    if (blockIdx.x == 195){
        for (int j = threadIdx.x; j < HC * C_OUT; j += 256){
            int k = j / C_OUT, c = j % C_OUT;
            W2t[c * HC + k] = W2[j];
        }
    }
}

// ---- GEMM1: xh1[N,256] = x[N,128] @ W1[128,256]; fp32 math, bf16 packed out,
//      attention scores computed EXACTLY from fp32 accumulators (epilogue) ----
__global__ __launch_bounds__(256) void k_gemm1(const float* __restrict__ x,
                                               const float* __restrict__ W,
                                               const float* __restrict__ atts,
                                               const float* __restrict__ attd,
                                               unsigned int* __restrict__ xhb,
                                               float* __restrict__ a_s,
                                               float* __restrict__ a_d){
    const int tx = threadIdx.x & 15;    // col group (4 cols)
    const int ty = threadIdx.x >> 4;    // row group (4 rows)
    const int bx = blockIdx.x & 3;      // 4 col blocks of 64
    const int by = blockIdx.x >> 2;
    const int c0 = bx * 64 + tx * 4;
    const int r0 = by * 64 + ty * 4;
    const float* xr0; const float* xr1; const float* xr2; const float* xr3;
    {
        int r = r0;     if (r >= N_NODES) r = N_NODES - 1; xr0 = x + (size_t)r * F_IN;
        r = r0 + 1;     if (r >= N_NODES) r = N_NODES - 1; xr1 = x + (size_t)r * F_IN;
        r = r0 + 2;     if (r >= N_NODES) r = N_NODES - 1; xr2 = x + (size_t)r * F_IN;
        r = r0 + 3;     if (r >= N_NODES) r = N_NODES - 1; xr3 = x + (size_t)r * F_IN;
    }
    const float* Wp = W + c0;
    float acc[4][4] = {};
    #pragma unroll 8
    for (int k = 0; k < F_IN; k++){
        float4 b = *(const float4*)(Wp + (size_t)k * HC);
        float a0 = xr0[k], a1 = xr1[k], a2 = xr2[k], a3 = xr3[k];
        acc[0][0] += a0*b.x; acc[0][1] += a0*b.y; acc[0][2] += a0*b.z; acc[0][3] += a0*b.w;
        acc[1][0] += a1*b.x; acc[1][1] += a1*b.y; acc[1][2] += a1*b.z; acc[1][3] += a1*b.w;
        acc[2][0] += a2*b.x; acc[2][1] += a2*b.y; acc[2][2] += a2*b.z; acc[2][3] += a2*b.w;
        acc[3][0] += a3*b.x; acc[3][1] += a3*b.y; acc[3][2] += a3*b.z; acc[3][3] += a3*b.w;
    }
    const int h = c0 >> 5;  // head owning these 4 cols
    float as0 = atts[c0], as1v = atts[c0+1], as2 = atts[c0+2], as3 = atts[c0+3];
    float ad0 = attd[c0], ad1v = attd[c0+1], ad2 = attd[c0+2], ad3 = attd[c0+3];
    #pragma unroll
    for (int i = 0; i < 4; i++){
        int r = r0 + i;
        bool ok = (r < N_NODES);
        if (ok){
            uint2 o = make_uint2(pack2(acc[i][0], acc[i][1]), pack2(acc[i][2], acc[i][3]));
            *(uint2*)(xhb + (size_t)r * (HC/2) + c0/2) = o;
        }
        float ss = acc[i][0]*as0 + acc[i][1]*as1v + acc[i][2]*as2 + acc[i][3]*as3;
        float dd = acc[i][0]*ad0 + acc[i][1]*ad1v + acc[i][2]*ad2 + acc[i][3]*ad3;
        ss += __shfl_xor(ss, 1, 64); ss += __shfl_xor(ss, 2, 64); ss += __shfl_xor(ss, 4, 64);
        dd += __shfl_xor(dd, 1, 64); dd += __shfl_xor(dd, 2, 64); dd += __shfl_xor(dd, 4, 64);
        if (ok && (tx & 7) == 0){
            atomicAdd(a_s + (size_t)r * NH + h, ss);
            atomicAdd(a_d + (size_t)r * NH + h, dd);
        }
    }
}

// ---- CSR build: degree histogram ----
__global__ void k_deg(const int* __restrict__ ei, int* __restrict__ deg){
    int e = blockIdx.x * 256 + threadIdx.x;
    if (e >= E_TOT) return;
    int dst = (e < N_EDGES) ? ei[N_EDGES + e] : (e - N_EDGES);
    atomicAdd(deg + dst, 1);
}

// ---- per-1024-chunk sums ----
__global__ void k_bsum(const int* __restrict__ deg, int* __restrict__ bsum){
    int b = blockIdx.x;
    int v = 0;
    for (int i = threadIdx.x; i < 1024; i += 256){
        int idx = b * 1024 + i;
        if (idx < N_NODES) v += deg[idx];
    }
    #pragma unroll
    for (int off = 1; off < 64; off <<= 1) v += __shfl_xor(v, off, 64);
    __shared__ int sd[4];
    if ((threadIdx.x & 63) == 0) sd[threadIdx.x >> 6] = v;
    __syncthreads();
    if (threadIdx.x == 0) bsum[b] = sd[0] + sd[1] + sd[2] + sd[3];
}

// ---- scan of chunk sums (single wave) ----
__global__ void k_scanb(const int* __restrict__ bsum, int* __restrict__ bexcl, int* __restrict__ rowp){
    int l = threadIdx.x;            // 64 threads
    int v = (l < NBLK) ? bsum[l] : 0;
    int incl = v;
    #pragma unroll
    for (int off = 1; off < 64; off <<= 1){
        int t = __shfl_up(incl, off, 64);
        if (l >= off) incl += t;
    }
    if (l < NBLK) bexcl[l] = incl - v;
    if (l == 0) rowp[N_NODES] = E_TOT;
}

// ---- per-chunk Hillis-Steele scan -> row_ptr, cursor ----
__global__ __launch_bounds__(1024) void k_scan(const int* __restrict__ deg, const int* __restrict__ bexcl,
                                               int* __restrict__ rowp, int* __restrict__ cur){
    __shared__ int sd[1024];
    int b = blockIdx.x;
    int i = b * 1024 + threadIdx.x;
    int v = (i < N_NODES) ? deg[i] : 0;
    sd[threadIdx.x] = v;
    __syncthreads();
    for (int off = 1; off < 1024; off <<= 1){
        int t = (threadIdx.x >= off) ? sd[threadIdx.x - off] : 0;
        __syncthreads();
        sd[threadIdx.x] += t;
        __syncthreads();
    }
    if (i < N_NODES){
        int excl = sd[threadIdx.x] - v + bexcl[b];
        rowp[i] = excl;
        cur[i]  = excl;
    }
}

// ---- scatter edges into CSR (src values) ----
__global__ void k_scatter(const int* __restrict__ ei, int* __restrict__ cur, int* __restrict__ col){
    int e = blockIdx.x * 256 + threadIdx.x;
    if (e >= E_TOT) return;
    int s, d;
    if (e < N_EDGES){ s = ei[e]; d = ei[N_EDGES + e]; }
    else { s = e - N_EDGES; d = s; }
    int slot = atomicAdd(cur + d, 1);
    col[slot] = s;
}

// ---- layer-1 aggregation: wave per dst node; bf16 message gather, fp32 out ----
__global__ __launch_bounds__(256) void k_agg1(const unsigned int* __restrict__ xhb,
                                              const float* __restrict__ a_s, const float* __restrict__ a_d,
                                              const int* __restrict__ rowp, const int* __restrict__ col,
                                              const float* __restrict__ bias, float* __restrict__ h1){
    int wave = threadIdx.x >> 6, lane = threadIdx.x & 63;
    int n = blockIdx.x * 4 + wave;
    if (n >= N_NODES) return;
    int h = lane >> 3;
    float adh = a_d[(size_t)n * NH + h];
    int s0 = rowp[n], s1 = rowp[n + 1];
    const uint2* xv = (const uint2*)xhb;   // row = 64 uint2
    float ax = 0.f, ay = 0.f, az = 0.f, aw = 0.f;
    float den = 0.f;
    for (int idx = s0; idx < s1; idx++){
        int s = col[idx];
        float w = __expf(lrelu(a_s[(size_t)s * NH + h] + adh));
        den += w;
        uint2 p = xv[(size_t)s * 64 + lane];
        float v0, v1, v2, v3;
        unp2(p.x, v0, v1); unp2(p.y, v2, v3);
        ax += w * v0; ay += w * v1; az += w * v2; aw += w * v3;
    }
    float rden = 1.f / den;
    float4 bb = ((const float4*)bias)[lane];
    float4 r;
    r.x = elu1(ax * rden + bb.x);
    r.y = elu1(ay * rden + bb.y);
    r.z = elu1(az * rden + bb.z);
    r.w = elu1(aw * rden + bb.w);
    ((float4*)h1)[(size_t)n * 64 + lane] = r;
}

// ---- layer-2 projection + attention scalars: wave per node (fp32 h1) ----
__global__ __launch_bounds__(256) void k_gemm2(const float* __restrict__ h1, const float* __restrict__ W2t,
                                               const float* __restrict__ atts, const float* __restrict__ attd,
                                               float* __restrict__ xh2, float* __restrict__ a_s, float* __restrict__ a_d){
    int wave = threadIdx.x >> 6, lane = threadIdx.x & 63;
    int n = blockIdx.x * 4 + wave;
    if (n >= N_NODES) return;
    float4 hv = ((const float4*)h1)[(size_t)n * 64 + lane];
    float acc[C_OUT];
    #pragma unroll
    for (int c = 0; c < C_OUT; c++){
        float4 w = ((const float4*)(W2t + c * HC))[lane];
        acc[c] = hv.x*w.x + hv.y*w.y + hv.z*w.z + hv.w*w.w;
    }
    #pragma unroll
    for (int c = 0; c < C_OUT; c++){
        #pragma unroll
        for (int off = 32; off > 0; off >>= 1) acc[c] += __shfl_xor(acc[c], off, 64);
    }
    if (lane == 0){
        float s = 0.f, d = 0.f;
        #pragma unroll
        for (int c = 0; c < C_OUT; c++){
            xh2[(size_t)n * C_OUT + c] = acc[c];
            s += acc[c] * atts[c];
            d += acc[c] * attd[c];
        }
        a_s[n] = s; a_d[n] = d;
    }
}

// ---- layer-2 aggregation + elu -> per-node h2[N,10] (no atomics) ----
__global__ __launch_bounds__(256) void k_agg2(const float* __restrict__ xh2,
                                              const float* __restrict__ a_s, const float* __restrict__ a_d,
                                              const int* __restrict__ rowp, const int* __restrict__ col,
                                              const float* __restrict__ b2,
                                              float* __restrict__ h2){
    int wave = threadIdx.x >> 6, lane = threadIdx.x & 63;
    int n = blockIdx.x * 4 + wave;
    if (n >= N_NODES) return;
    float adn = a_d[n];
    int s0 = rowp[n], s1 = rowp[n + 1];
    float acc[C_OUT] = {};
    float den = 0.f;
    for (int idx = s0 + lane; idx < s1; idx += 64){
        int s = col[idx];
        float w = __expf(lrelu(a_s[s] + adn));
        den += w;
        const float* xr = xh2 + (size_t)s * C_OUT;
        #pragma unroll
        for (int c = 0; c < C_OUT; c++) acc[c] += w * xr[c];
    }
    #pragma unroll
    for (int off = 32; off > 0; off >>= 1) den += __shfl_xor(den, off, 64);
    #pragma unroll
    for (int c = 0; c < C_OUT; c++){
        #pragma unroll
        for (int off = 32; off > 0; off >>= 1) acc[c] += __shfl_xor(acc[c], off, 64);
    }
    if (lane == 0){
        float rden = 1.f / den;
        #pragma unroll
        for (int c = 0; c < C_OUT; c++)
            h2[(size_t)n * C_OUT + c] = elu1(acc[c] * rden + b2[c]);
    }
}

// ---- pooling + log_softmax: one block per graph (batch is sorted) ----
__global__ __launch_bounds__(256) void k_pool(const float* __restrict__ h2, const int* __restrict__ batch,
                                              float* __restrict__ out){
    int g = blockIdx.x;
    int l = 0, r = N_NODES;
    while (l < r){ int m = (l + r) >> 1; if (batch[m] < g) l = m + 1; else r = m; }
    int lo = l;
    l = 0; r = N_NODES;
    while (l < r){ int m = (l + r) >> 1; if (batch[m] < g + 1) l = m + 1; else r = m; }
    int hi = l;
    float acc[C_OUT] = {};
    for (int i = lo + (int)threadIdx.x; i < hi; i += 256){
        const float* row = h2 + (size_t)i * C_OUT;
        #pragma unroll
        for (int c = 0; c < C_OUT; c++) acc[c] += row[c];
    }
    #pragma unroll
    for (int c = 0; c < C_OUT; c++){
        #pragma unroll
        for (int off = 32; off > 0; off >>= 1) acc[c] += __shfl_xor(acc[c], off, 64);
    }
    __shared__ float sd[4][C_OUT];
    int wave = threadIdx.x >> 6, lane = threadIdx.x & 63;
    if (lane == 0){
        #pragma unroll
        for (int c = 0; c < C_OUT; c++) sd[wave][c] = acc[c];
    }
    __syncthreads();
    if (threadIdx.x == 0){
        float cnt = (float)(hi - lo);
        if (cnt < 1.f) cnt = 1.f;
        float v[C_OUT];
        float m = -1e30f;
        #pragma unroll
        for (int c = 0; c < C_OUT; c++){
            v[c] = (sd[0][c] + sd[1][c] + sd[2][c] + sd[3][c]) / cnt;
            m = fmaxf(m, v[c]);
        }
        float sum = 0.f;
        #pragma unroll
        for (int c = 0; c < C_OUT; c++) sum += __expf(v[c] - m);
        float lse = m + __logf(sum);
        #pragma unroll
        for (int c = 0; c < C_OUT; c++) out[g * C_OUT + c] = v[c] - lse;
    }
}

extern "C" void kernel_launch(void* const* d_in, const int* in_sizes, int n_in,
                              void* d_out, int out_size, void* d_ws, size_t ws_size,
                              hipStream_t stream){
    const float* x    = (const float*)d_in[0];
    const int*   ei   = (const int*)d_in[1];
    const int*   batch= (const int*)d_in[2];
    const float* W1   = (const float*)d_in[3];
    const float* as1  = (const float*)d_in[4];
    const float* ad1  = (const float*)d_in[5];
    const float* b1   = (const float*)d_in[6];
    const float* W2   = (const float*)d_in[7];
    const float* as2v = (const float*)d_in[8];
    const float* ad2v = (const float*)d_in[9];
    const float* b2   = (const float*)d_in[10];
    float* out = (float*)d_out;

    char* ws = (char*)d_ws;
    size_t off = 0;
    auto alloc = [&](size_t bytes)->char*{
        char* p = ws + off;
        off = (off + bytes + 255) & ~(size_t)255;
        return p;
    };
    unsigned int* xh1b = (unsigned int*)alloc((size_t)N_NODES * HC * 2);  // bf16 gather table
    float* h1   = (float*)alloc((size_t)N_NODES * HC * 4);                // fp32
    float* asc1 = (float*)alloc((size_t)N_NODES * NH * 4);
    float* adc1 = (float*)alloc((size_t)N_NODES * NH * 4);
    int*   deg  = (int*)alloc((size_t)N_NODES * 4);
    int*   rowp = (int*)alloc((size_t)(N_NODES + 1) * 4);
    int*   cur  = (int*)alloc((size_t)N_NODES * 4);
    int*   col  = (int*)alloc((size_t)E_TOT * 4);
    int*   bsum = (int*)alloc(64 * 4);
    int*   bexcl= (int*)alloc(64 * 4);
    float* xh2  = (float*)alloc((size_t)N_NODES * C_OUT * 4);
    float* asc2 = (float*)alloc((size_t)N_NODES * 4);
    float* adc2 = (float*)alloc((size_t)N_NODES * 4);
    float* W2t  = (float*)alloc((size_t)HC * C_OUT * 4);
    float* h2   = (float*)alloc((size_t)N_NODES * C_OUT * 4);
    (void)ws_size; (void)in_sizes; (void)n_in; (void)out_size;

    hipLaunchKernelGGL(k_init,    dim3(196),  dim3(256), 0, stream, deg, asc1, adc1, W2, W2t);
    hipLaunchKernelGGL(k_gemm1,   dim3(3128), dim3(256), 0, stream, x, W1, as1, ad1, xh1b, asc1, adc1);
    hipLaunchKernelGGL(k_deg,     dim3((E_TOT + 255)/256), dim3(256), 0, stream, ei, deg);
    hipLaunchKernelGGL(k_bsum,    dim3(NBLK), dim3(256), 0, stream, deg, bsum);
    hipLaunchKernelGGL(k_scanb,   dim3(1),    dim3(64),  0, stream, bsum, bexcl, rowp);
    hipLaunchKernelGGL(k_scan,    dim3(NBLK), dim3(1024),0, stream, deg, bexcl, rowp, cur);
    hipLaunchKernelGGL(k_scatter, dim3((E_TOT + 255)/256), dim3(256), 0, stream, ei, cur, col);
    hipLaunchKernelGGL(k_agg1,    dim3((N_NODES + 3)/4), dim3(256), 0, stream, xh1b, asc1, adc1, rowp, col, b1, h1);
    hipLaunchKernelGGL(k_gemm2,   dim3((N_NODES + 3)/4), dim3(256), 0, stream, h1, W2t, as2v, ad2v, xh2, asc2, adc2);
    hipLaunchKernelGGL(k_agg2,    dim3((N_NODES + 3)/4), dim3(256), 0, stream, xh2, asc2, adc2, rowp, col, b2, h2);
    hipLaunchKernelGGL(k_pool,    dim3(N_GRAPH), dim3(256), 0, stream, h2, batch, out);
}